// Round 1
// baseline (77.655 us; speedup 1.0000x reference)
//
#include <hip/hip_runtime.h>
#include <math.h>

// Problem constants (from reference): keypoints [B,3,M] f32, pc [B,3,N] f32.
#define BATCH 4
#define M 1024
#define N 32768
#define NSPLIT 128                 // pc chunks per batch
#define CHUNK (N / NSPLIT)         // 256 points staged in LDS per block
#define KPT 4                      // keypoints per thread (256 thr * 4 = 1024 = M)
#define TPB 256

// ws layout: [B*M] uint  (float bits of min squared distance) = 16 KB
__global__ void p2p_init(unsigned* __restrict__ wsmin) {
    int i = blockIdx.x * blockDim.x + threadIdx.x;
    if (i < BATCH * M) wsmin[i] = 0x7F800000u;  // +inf
}

__global__ __launch_bounds__(TPB) void p2p_partial(
        const float* __restrict__ kp, const float* __restrict__ pc,
        unsigned* __restrict__ wsmin) {
    __shared__ __align__(16) float px[CHUNK];
    __shared__ __align__(16) float py[CHUNK];
    __shared__ __align__(16) float pz[CHUNK];

    const int b = blockIdx.x / NSPLIT;
    const int c = blockIdx.x % NSPLIT;
    const int t = threadIdx.x;

    // Stage one pc chunk into LDS (coalesced: 3 loads/thread).
    const float* pcb = pc + (size_t)b * 3 * N + c * CHUNK;
    px[t] = pcb[t];
    py[t] = pcb[N + t];
    pz[t] = pcb[2 * N + t];

    // Each thread owns KPT keypoints in registers (coalesced loads).
    const float* kpb = kp + (size_t)b * 3 * M;
    float kx[KPT], ky[KPT], kz[KPT], md[KPT];
#pragma unroll
    for (int k = 0; k < KPT; ++k) {
        int m = t + k * TPB;
        kx[k] = kpb[m];
        ky[k] = kpb[M + m];
        kz[k] = kpb[2 * M + m];
        md[k] = INFINITY;
    }
    __syncthreads();

    // Hot loop: 4 points per iteration via float4 broadcast LDS reads.
    // 3 ds_read_b128 + 16 pairs * 7 VALU = 112 VALU per iter -> VALU-bound.
#pragma unroll 1
    for (int j = 0; j < CHUNK; j += 4) {
        float4 vx = *(const float4*)&px[j];
        float4 vy = *(const float4*)&py[j];
        float4 vz = *(const float4*)&pz[j];
        float X[4] = {vx.x, vx.y, vx.z, vx.w};
        float Y[4] = {vy.x, vy.y, vy.z, vy.w};
        float Z[4] = {vz.x, vz.y, vz.z, vz.w};
#pragma unroll
        for (int p = 0; p < 4; ++p) {
#pragma unroll
            for (int k = 0; k < KPT; ++k) {
                float dx = kx[k] - X[p];
                float dy = ky[k] - Y[p];
                float dz = kz[k] - Z[p];
                float d2 = fmaf(dx, dx, fmaf(dy, dy, dz * dz));
                md[k] = fminf(md[k], d2);
            }
        }
    }

    // Order-independent (deterministic) combine across chunk-blocks:
    // uint compare == float compare for non-negative floats.
#pragma unroll
    for (int k = 0; k < KPT; ++k) {
        atomicMin(&wsmin[b * M + t + k * TPB], __float_as_uint(md[k]));
    }
}

__global__ __launch_bounds__(1024) void p2p_reduce(
        const unsigned* __restrict__ wsmin, float* __restrict__ out) {
    __shared__ float sbuf[1024 / 64];
    const int t = threadIdx.x;
    float s = 0.f;
#pragma unroll
    for (int i = t; i < BATCH * M; i += 1024)
        s += sqrtf(__uint_as_float(wsmin[i]));
    // wave64 shuffle reduce
#pragma unroll
    for (int off = 32; off > 0; off >>= 1) s += __shfl_down(s, off, 64);
    if ((t & 63) == 0) sbuf[t >> 6] = s;
    __syncthreads();
    if (t == 0) {
        float tot = 0.f;
#pragma unroll
        for (int w = 0; w < 1024 / 64; ++w) tot += sbuf[w];
        out[0] = tot / (float)(BATCH * M);
    }
}

extern "C" void kernel_launch(void* const* d_in, const int* in_sizes, int n_in,
                              void* d_out, int out_size, void* d_ws, size_t ws_size,
                              hipStream_t stream) {
    const float* kp = (const float*)d_in[0];   // [B,3,M]
    const float* pc = (const float*)d_in[1];   // [B,3,N]
    float* out = (float*)d_out;
    unsigned* wsmin = (unsigned*)d_ws;         // 16 KB

    p2p_init<<<(BATCH * M + 255) / 256, 256, 0, stream>>>(wsmin);
    p2p_partial<<<BATCH * NSPLIT, TPB, 0, stream>>>(kp, pc, wsmin);
    p2p_reduce<<<1, 1024, 0, stream>>>(wsmin, out);
}